// Round 4
// baseline (110.221 us; speedup 1.0000x reference)
//
#include <hip/hip_runtime.h>
#include <math.h>

#define F 128
#define D 256
#define N_CATE 18
#define P 8

// ---------------- lean sort-by-dst pipeline --------------------------------
// cnt[N_DST] histogram -> single-block exclusive scan -> payload scatter.

__global__ void hist_kernel(const int* __restrict__ dst_idx,
                            int* __restrict__ cnt, int E) {
    int e = blockIdx.x * blockDim.x + threadIdx.x;
    if (e < E) atomicAdd(&cnt[dst_idx[e]], 1);
}

// exclusive scan of cnt[0..nkey) in one 1024-thread block (nkey <= 16384)
__global__ __launch_bounds__(1024) void scan_kernel(int* __restrict__ cnt, int nkey) {
    const int t = threadIdx.x;
    const int per = (nkey + 1023) >> 10;
    const int base = t * per;
    // pass 1: per-thread total
    int ts = 0;
    for (int i = 0; i < per; ++i) {
        int idx = base + i;
        if (idx < nkey) ts += cnt[idx];
    }
    // wave inclusive scan
    int x = ts;
    const int lane = t & 63;
#pragma unroll
    for (int m = 1; m < 64; m <<= 1) {
        int y = __shfl_up(x, m, 64);
        if (lane >= m) x += y;
    }
    __shared__ int wsum[16];
    if (lane == 63) wsum[t >> 6] = x;
    __syncthreads();
    int off = 0;
    for (int w0 = 0; w0 < (t >> 6); ++w0) off += wsum[w0];
    int excl = off + x - ts;
    // pass 2: rewrite with running exclusive prefix (no local array)
    for (int i = 0; i < per; ++i) {
        int idx = base + i;
        if (idx < nkey) {
            int v = cnt[idx];
            cnt[idx] = excl;
            excl += v;
        }
    }
}

__global__ void scatter_kernel(const int* __restrict__ src_idx,
                               const int* __restrict__ dst_idx,
                               const int* __restrict__ cate_id,
                               int* __restrict__ cnt,
                               int* __restrict__ s_sorted,
                               int* __restrict__ k_sorted,
                               int* __restrict__ e_sorted, int E) {
    int e = blockIdx.x * blockDim.x + threadIdx.x;
    if (e >= E) return;
    int d = dst_idx[e];
    int s = src_idx[e];
    int c = cate_id[s];
    int pos = atomicAdd(&cnt[d], 1);
    s_sorted[pos] = s;
    k_sorted[pos] = (d << 5) | c;   // d < 2^14, c < 18
    e_sorted[pos] = e;
}

// ---------------- main kernel ----------------------------------------------
// Lane layout: lane = 8*p + j. out = sqrt(F) * softmax-weighted mean of s_p,
// s_p = (w_p*(src.pref_p) + (1-w_p)*(src.dst)) / sqrt(F).
__global__ __launch_bounds__(256) void score_predictor_kernel(
    const float* __restrict__ gnn_emb_src,   // (N_SRC, D)
    const float* __restrict__ gnn_emb_dst,   // (N_DST, D)
    const float* __restrict__ news_pref,     // (N_DST, N_CATE, P, D)
    const float* __restrict__ last_update,   // (N_DST, N_CATE, P)
    const float* __restrict__ time_arr,      // (E,)
    const int*   __restrict__ cate_id,       // (N_SRC,)  (fallback path)
    const int*   __restrict__ src_idx,       // (E,)      (fallback path)
    const int*   __restrict__ dst_idx,       // (E,)      (fallback path)
    const int*   __restrict__ s_sorted,      // (E,) or NULL
    const int*   __restrict__ k_sorted,      // (E,)
    const int*   __restrict__ e_sorted,      // (E,)
    float* __restrict__ out,
    int E)
{
    // bijective chunked XCD swizzle: contiguous sorted range per XCD
    const int B = (int)gridDim.x;
    const int bid = (int)blockIdx.x;
    const int q = B >> 3, r = B & 7;
    const int xcd = bid & 7, pos = bid >> 3;
    const int nb = (xcd < r) ? (xcd * (q + 1)) : (r * (q + 1) + (xcd - r) * q);
    const int sb = nb + pos;

    const int w = sb * 4 + (int)(threadIdx.x >> 6);
    const int lane = (int)(threadIdx.x & 63);
    if (w >= E) return;

    int s, d, c, e;
    if (s_sorted) {
        s = s_sorted[w];
        const int k = k_sorted[w];
        e = e_sorted[w];
        d = k >> 5;
        c = k & 31;
    } else {
        e = w;
        s = src_idx[e];
        d = dst_idx[e];
        c = cate_id[s];
    }

    const int p = lane >> 3;
    const int j = lane & 7;
    const float t0 = time_arr[0];

    const float* __restrict__ srow = gnn_emb_src + (size_t)s * D;
    const float* __restrict__ drow = gnn_emb_dst + (size_t)d * D;
    const size_t dc = (size_t)d * N_CATE + (size_t)c;
    const float* __restrict__ prow = news_pref + dc * (size_t)(P * D) + (size_t)p * D;

    const float wp = __expf(last_update[dc * P + p] - t0);
    const float omw = 1.0f - wp;

    float qp = 0.0f, tp = 0.0f;
#pragma unroll
    for (int k = 0; k < 4; ++k) {
        const int off = k * 32 + j * 4;
        const float4 sv = *(const float4*)(srow + off);
        const float4 dv = *(const float4*)(drow + off);
        const float4 pv = *(const float4*)(prow + off);
        qp += sv.x * pv.x + sv.y * pv.y + sv.z * pv.z + sv.w * pv.w;
        tp += sv.x * dv.x + sv.y * dv.y + sv.z * dv.z + sv.w * dv.w;
    }

#pragma unroll
    for (int m = 1; m <= 4; m <<= 1) {
        qp += __shfl_xor(qp, m, 64);
        tp += __shfl_xor(tp, m, 64);
    }

    const float inv_sqrtF = 0.088388347648318447f; // 1/sqrt(128)
    const float sp = (wp * qp + omw * tp) * inv_sqrtF;

    float mx = sp;
#pragma unroll
    for (int m = 8; m <= 32; m <<= 1) {
        mx = fmaxf(mx, __shfl_xor(mx, m, 64));
    }

    const float ep = __expf(sp - mx);
    float num = ep * sp;
    float den = ep;
#pragma unroll
    for (int m = 8; m <= 32; m <<= 1) {
        num += __shfl_xor(num, m, 64);
        den += __shfl_xor(den, m, 64);
    }

    if (lane == 0) {
        out[e] = (num / den) * 11.313708498984761f; // sqrt(128)
    }
}

extern "C" void kernel_launch(void* const* d_in, const int* in_sizes, int n_in,
                              void* d_out, int out_size, void* d_ws, size_t ws_size,
                              hipStream_t stream) {
    const float* gnn_emb_src = (const float*)d_in[0];
    const float* gnn_emb_dst = (const float*)d_in[1];
    const float* news_pref   = (const float*)d_in[2];
    const float* last_update = (const float*)d_in[3];
    const float* time_arr    = (const float*)d_in[4];
    const int*   cate_id     = (const int*)d_in[5];
    const int*   src_idx     = (const int*)d_in[6];
    const int*   dst_idx     = (const int*)d_in[7];
    float* out = (float*)d_out;

    const int E = in_sizes[6];
    const int N_DST = in_sizes[1] / D;

    // ws layout: cnt[N_DST] | s_sorted[E] | k_sorted[E] | e_sorted[E]
    const size_t need = ((size_t)N_DST + 3 * (size_t)E) * sizeof(int);

    int *s_sorted = nullptr, *k_sorted = nullptr, *e_sorted = nullptr;
    if (ws_size >= need && N_DST <= 16384 && N_DST < (1 << 14) + 1) {
        int* cnt = (int*)d_ws;
        s_sorted = cnt + N_DST;
        k_sorted = s_sorted + E;
        e_sorted = k_sorted + E;

        hipMemsetAsync(cnt, 0, (size_t)N_DST * sizeof(int), stream);
        hist_kernel<<<(E + 255) / 256, 256, 0, stream>>>(dst_idx, cnt, E);
        scan_kernel<<<1, 1024, 0, stream>>>(cnt, N_DST);
        scatter_kernel<<<(E + 255) / 256, 256, 0, stream>>>(
            src_idx, dst_idx, cate_id, cnt, s_sorted, k_sorted, e_sorted, E);
    }

    const int waves_per_block = 256 / 64;
    const int grid = (E + waves_per_block - 1) / waves_per_block;

    score_predictor_kernel<<<grid, 256, 0, stream>>>(
        gnn_emb_src, gnn_emb_dst, news_pref, last_update, time_arr,
        cate_id, src_idx, dst_idx, s_sorted, k_sorted, e_sorted, out, E);
}

// Round 5
// 80.027 us; speedup vs baseline: 1.3773x; 1.3773x over previous
//
#include <hip/hip_runtime.h>
#include <math.h>

#define F 128
#define D 256
#define N_CATE 18
#define P 8

// One 64-lane wave per edge. Lane layout: lane = 8*p + j
//   p in [0,8) = pref row, j in [0,8) = feature chunk (float4 at k*32 + j*4).
//
// Math collapse: src.pe_p = w_p*(src.pref_p) + (1-w_p)*(src.dst) = s_p*sqrt(F)
//   out = sqrt(F) * (sum_p e_p s_p) / (sum_p e_p),  e_p = exp(s_p - max_p s_p)
//
// Memory-bound roofline: ~5.07 KB gathered per edge x 100k edges = 507 MB
// at ~6.4 TB/s achievable = ~79 us. Sort-based dedup attempts (rounds 3-4)
// cost 27-31 us in pipeline overhead vs <=20 us max locality gain — net loss.
__global__ __launch_bounds__(256) void score_predictor_kernel(
    const float* __restrict__ gnn_emb_src,   // (N_SRC, D)
    const float* __restrict__ gnn_emb_dst,   // (N_DST, D)
    const float* __restrict__ news_pref,     // (N_DST, N_CATE, P, D)
    const float* __restrict__ last_update,   // (N_DST, N_CATE, P)
    const float* __restrict__ time_arr,      // (E,)
    const int*   __restrict__ cate_id,       // (N_SRC,)
    const int*   __restrict__ src_idx,       // (E,)
    const int*   __restrict__ dst_idx,       // (E,)
    float* __restrict__ out,
    int E)
{
    const int e = (int)((blockIdx.x * blockDim.x + threadIdx.x) >> 6);
    const int lane = (int)(threadIdx.x & 63);
    if (e >= E) return;
    const int p = lane >> 3;
    const int j = lane & 7;

    // Wave-uniform scalars
    const int s = src_idx[e];
    const int d = dst_idx[e];
    const int c = cate_id[s];
    const float t0 = time_arr[0];

    const float* __restrict__ srow = gnn_emb_src + (size_t)s * D;
    const float* __restrict__ drow = gnn_emb_dst + (size_t)d * D;
    const size_t dc = (size_t)d * N_CATE + (size_t)c;
    const float* __restrict__ prow = news_pref + dc * (size_t)(P * D) + (size_t)p * D;

    // decay weight for this lane's p (uniform within each 8-lane group)
    const float wp = __expf(last_update[dc * P + p] - t0);
    const float omw = 1.0f - wp;

    // partial dots: q_p = src . pref_p, t = src . dst  (16 features per lane)
    float qp = 0.0f, tp = 0.0f;
#pragma unroll
    for (int k = 0; k < 4; ++k) {
        const int off = k * 32 + j * 4;
        const float4 sv = *(const float4*)(srow + off);
        const float4 dv = *(const float4*)(drow + off);
        const float4 pv = *(const float4*)(prow + off);
        qp += sv.x * pv.x + sv.y * pv.y + sv.z * pv.z + sv.w * pv.w;
        tp += sv.x * dv.x + sv.y * dv.y + sv.z * dv.z + sv.w * dv.w;
    }

    // reduce (qp, tp) over j (lane bits 0..2): 6 shfl
#pragma unroll
    for (int m = 1; m <= 4; m <<= 1) {
        qp += __shfl_xor(qp, m, 64);
        tp += __shfl_xor(tp, m, 64);
    }

    // score for this lane's p (replicated across its 8-lane group)
    const float inv_sqrtF = 0.088388347648318447f; // 1/sqrt(128)
    const float sp = (wp * qp + omw * tp) * inv_sqrtF;

    // max over p (lane bits 3..5): 3 shfl
    float mx = sp;
#pragma unroll
    for (int m = 8; m <= 32; m <<= 1) {
        mx = fmaxf(mx, __shfl_xor(mx, m, 64));
    }

    // softmax-weighted average of s_p: 6 shfl
    const float ep = __expf(sp - mx);
    float num = ep * sp;
    float den = ep;
#pragma unroll
    for (int m = 8; m <= 32; m <<= 1) {
        num += __shfl_xor(num, m, 64);
        den += __shfl_xor(den, m, 64);
    }

    if (lane == 0) {
        out[e] = (num / den) * 11.313708498984761f; // sqrt(128)
    }
}

extern "C" void kernel_launch(void* const* d_in, const int* in_sizes, int n_in,
                              void* d_out, int out_size, void* d_ws, size_t ws_size,
                              hipStream_t stream) {
    const float* gnn_emb_src = (const float*)d_in[0];
    const float* gnn_emb_dst = (const float*)d_in[1];
    const float* news_pref   = (const float*)d_in[2];
    const float* last_update = (const float*)d_in[3];
    const float* time_arr    = (const float*)d_in[4];
    const int*   cate_id     = (const int*)d_in[5];
    const int*   src_idx     = (const int*)d_in[6];
    const int*   dst_idx     = (const int*)d_in[7];
    float* out = (float*)d_out;

    const int E = in_sizes[6];           // src_idx length
    const int waves_per_block = 256 / 64;
    const int grid = (E + waves_per_block - 1) / waves_per_block;

    score_predictor_kernel<<<grid, 256, 0, stream>>>(
        gnn_emb_src, gnn_emb_dst, news_pref, last_update, time_arr,
        cate_id, src_idx, dst_idx, out, E);
}